// Round 6
// baseline (413.814 us; speedup 1.0000x reference)
//
#include <hip/hip_runtime.h>
#include <hip/hip_bf16.h>
#include <math.h>

// Problem constants
#define NB   2
#define CIN  256
#define CC   512
#define GG   8
#define CGR  64
#define HH   48
#define WW   48
#define PP   (HH*WW)        // 2304
#define HD   46
#define WD   46
#define DD   (HD*WD)        // 2116
#define DPADV 2120          // v row stride (16B-aligned rows)
#define WRT  589824         // 512*9*128, per-tensor reordered weight stride

typedef __bf16 bf16x8 __attribute__((ext_vector_type(8)));
typedef __bf16 bf16x4 __attribute__((ext_vector_type(4)));
typedef float  f32x4  __attribute__((ext_vector_type(4)));

__device__ __forceinline__ bf16x8 ldb8(const __hip_bfloat16* p) {
    return *reinterpret_cast<const bf16x8*>(p);
}
__device__ __forceinline__ void store4bf(__hip_bfloat16* p, f32x4 v) {
    union { __hip_bfloat16 h[4]; uint2 u; } t;
    #pragma unroll
    for (int r = 0; r < 4; ++r) t.h[r] = (__hip_bfloat16)v[r];
    *reinterpret_cast<uint2*>(p) = t.u;
}

// ---------------------------------------------------------------------------
// Kernel 0: weight prep (unchanged).
// ---------------------------------------------------------------------------
__global__ __launch_bounds__(256) void prep_kernel(
    const float* __restrict__ Wq, const float* __restrict__ Wk,
    const float* __restrict__ Wv, const float* __restrict__ Wix,
    const float* __restrict__ Wfx, const float* __restrict__ Wgx,
    const float* __restrict__ Wox, const float* __restrict__ Wia,
    const float* __restrict__ Wfa, const float* __restrict__ Wga,
    const float* __restrict__ Woa, const float* __restrict__ Wx,
    const float* __restrict__ Wig,
    __hip_bfloat16* __restrict__ Wr, __hip_bfloat16* __restrict__ Wa,
    __hip_bfloat16* __restrict__ Wp)
{
    const int i = blockIdx.x * 256 + threadIdx.x;
    const int N1 = 7 * WRT;
    const int N2 = N1 + 4 * 32768;
    if (i < N1) {
        const int t = i / WRT, r = i % WRT;
        const int co = r / 1152, r2 = r % 1152;
        const int tap = r2 / 128, ci = r2 % 128;
        const float* src;
        switch (t) {
            case 0: src = Wq;  break;  case 1: src = Wk;  break;
            case 2: src = Wv;  break;  case 3: src = Wix; break;
            case 4: src = Wfx; break;  case 5: src = Wgx; break;
            default: src = Wox;
        }
        Wr[i] = (__hip_bfloat16)src[(size_t)co * 1152 + ci * 9 + tap];
    } else if (i < N2) {
        const int j = i - N1;
        const int t = j / 32768, r = j % 32768;
        const float* src = (t == 0) ? Wia : (t == 1) ? Wfa : (t == 2) ? Wga : Woa;
        Wa[j] = (__hip_bfloat16)src[r];
    } else {
        const int j = i - N2;
        const int c = j / 768, k = j % 768;
        Wp[j] = (__hip_bfloat16)((k < 256) ? Wx[(size_t)c * 256 + k]
                                           : Wig[(size_t)c * 512 + (k - 256)]);
    }
}

// ---------------------------------------------------------------------------
// Kernel 1a: transpose/convert (unchanged).
// ---------------------------------------------------------------------------
__global__ __launch_bounds__(256) void xpose_kernel(
    const float* __restrict__ x_in, const float* __restrict__ h,
    __hip_bfloat16* __restrict__ xiT, __hip_bfloat16* __restrict__ xhT)
{
    const int pt = blockIdx.x;
    const int n  = blockIdx.y;
    const int p0 = pt * 16;
    const int tid = threadIdx.x;

    __shared__ float xs[CIN * 17];
    __shared__ float hs[CC * 17];

    const float* xb = x_in + (size_t)n * CIN * PP;
    const float* hb = h + (size_t)n * CC * PP;
    #pragma unroll
    for (int k = 0; k < 16; ++k) {
        const int idx = k * 256 + tid;
        xs[(idx >> 4) * 17 + (idx & 15)] = xb[(size_t)(idx >> 4) * PP + p0 + (idx & 15)];
    }
    #pragma unroll
    for (int k = 0; k < 32; ++k) {
        const int idx = k * 256 + tid;
        hs[(idx >> 4) * 17 + (idx & 15)] = hb[(size_t)(idx >> 4) * PP + p0 + (idx & 15)];
    }
    __syncthreads();

    #pragma unroll
    for (int it = 0; it < 2; ++it) {
        const int u = it * 256 + tid;
        const int pix = u & 15, ck = u >> 4;
        union { __hip_bfloat16 h8[8]; bf16x8 v; } t;
        #pragma unroll
        for (int j = 0; j < 8; ++j)
            t.h8[j] = (__hip_bfloat16)xs[(ck * 8 + j) * 17 + pix];
        *reinterpret_cast<bf16x8*>(
            xiT + ((size_t)n * PP + p0 + pix) * 256 + ck * 8) = t.v;
    }
    #pragma unroll
    for (int it = 0; it < 4; ++it) {
        const int u = it * 256 + tid;
        const int pix = u & 15, ck = u >> 4;
        const int g = ck >> 3, c8 = (ck & 7) * 8;
        union { __hip_bfloat16 h8[8]; bf16x8 v; } t;
        #pragma unroll
        for (int j = 0; j < 8; ++j)
            t.h8[j] = (__hip_bfloat16)hs[(ck * 8 + j) * 17 + pix];
        *reinterpret_cast<bf16x8*>(
            xhT + ((size_t)(n * GG + g) * PP + p0 + pix) * 128 + 64 + c8) = t.v;
    }
}

// ---------------------------------------------------------------------------
// Kernel 1b: proj GEMM via MFMA (unchanged). grid 192 x 256.
// ---------------------------------------------------------------------------
__global__ __launch_bounds__(256) void proj_mfma_kernel(
    const __hip_bfloat16* __restrict__ xiT, const __hip_bfloat16* __restrict__ Wp,
    __hip_bfloat16* xhT)
{
    const int b = blockIdx.x;
    const int g = b & 7;
    const int j = b >> 3;
    const int n = j / 12;
    const int yt = j % 12;
    const int ng = n * GG + g;
    const int tid = threadIdx.x;
    const int w = tid >> 6, lane = tid & 63;
    const int col = lane & 15, quad = lane >> 4;
    const int y = yt * 4 + w;

    f32x4 acc[12];
    #pragma unroll
    for (int i = 0; i < 12; ++i) acc[i] = (f32x4){0.f, 0.f, 0.f, 0.f};

    const __hip_bfloat16* wbase = Wp + ((size_t)(g * 64) + col) * 768;

    for (int kk = 0; kk < 24; ++kk) {
        bf16x8 bfr[3];
        if (kk < 8) {
            const __hip_bfloat16* bp =
                xiT + ((size_t)n * PP + y * 48 + col) * 256 + kk * 32 + quad * 8;
            #pragma unroll
            for (int nf = 0; nf < 3; ++nf)
                bfr[nf] = ldb8(bp + (size_t)(nf * 16) * 256);
        } else {
            const int kh = kk - 8;
            const int gp = kh >> 1;
            const int c0 = (kh & 1) * 32;
            const __hip_bfloat16* bp =
                xhT + ((size_t)(n * GG + gp) * PP + y * 48 + col) * 128 + 64 + c0 + quad * 8;
            #pragma unroll
            for (int nf = 0; nf < 3; ++nf)
                bfr[nf] = ldb8(bp + (size_t)(nf * 16) * 128);
        }
        const __hip_bfloat16* wp = wbase + kk * 32 + quad * 8;
        #pragma unroll
        for (int cf = 0; cf < 4; ++cf) {
            const bf16x8 af = ldb8(wp + (size_t)(cf * 16) * 768);
            #pragma unroll
            for (int nf = 0; nf < 3; ++nf)
                acc[cf * 3 + nf] = __builtin_amdgcn_mfma_f32_16x16x32_bf16(
                    af, bfr[nf], acc[cf * 3 + nf], 0, 0, 0);
        }
    }

    __hip_bfloat16* dst = xhT + (size_t)ng * PP * 128;
    #pragma unroll
    for (int cf = 0; cf < 4; ++cf)
        #pragma unroll
        for (int nf = 0; nf < 3; ++nf) {
            const int pix = y * 48 + nf * 16 + col;
            store4bf(dst + (size_t)pix * 128 + cf * 16 + quad * 4, acc[cf * 3 + nf]);
        }
}

// ---------------------------------------------------------------------------
// Kernel 2: fused q/k/v grouped 3x3 conv via MFMA (q now scaled by tau).
// grid 576 x 256.
// ---------------------------------------------------------------------------
__global__ __launch_bounds__(256) void conv_qkv_kernel(
    const __hip_bfloat16* __restrict__ xhT, const __hip_bfloat16* __restrict__ Wr,
    const float* __restrict__ tau,
    __hip_bfloat16* __restrict__ qT, __hip_bfloat16* __restrict__ kT,
    __hip_bfloat16* __restrict__ v)
{
    const int b = blockIdx.x;
    const int xcd = b & 7;
    const int j = b >> 3;
    const int s = xcd + 8 * (j / 12);
    const int yt = j % 12;
    const int t = s / 16;
    const int ng = s % 16;
    const int g = ng & 7;
    const int tid = threadIdx.x;
    const int w = tid >> 6, lane = tid & 63;
    const int col = lane & 15, quad = lane >> 4;
    const int y0 = yt * 4;
    const int yy = y0 + w;
    const int ohw = (t == 0) ? 48 : 46;
    const int d0 = (t == 0) ? -1 : 0;
    const bool wave_active = (yy < ohw);

    __shared__ __hip_bfloat16 st[8 * 288 * 8];

    const __hip_bfloat16* slab = xhT + (size_t)ng * PP * 128;
    const __hip_bfloat16* wbase =
        Wr + (size_t)t * WRT + ((size_t)(g * 64) + col) * 1152;

    f32x4 acc[12];
    #pragma unroll
    for (int i = 0; i < 12; ++i) acc[i] = (f32x4){0.f, 0.f, 0.f, 0.f};

    for (int hc = 0; hc < 2; ++hc) {
        __syncthreads();
        #pragma unroll
        for (int it = 0; it < 9; ++it) {
            const int u = it * 256 + tid;
            const int lr = u / 384;
            const int rem = u % 384;
            const int px = rem >> 3, ck = rem & 7;
            int ry = y0 + d0 + lr;
            ry = max(0, min(47, ry));
            *reinterpret_cast<bf16x8*>(st + ((ck * 288) + lr * 48 + px) * 8) =
                ldb8(slab + ((size_t)(ry * 48 + px)) * 128 + hc * 64 + ck * 8);
        }
        __syncthreads();
        if (!wave_active) continue;

        for (int ky = 0; ky < 3; ++ky) {
            const int ry = yy + ky + d0;
            if (ry < 0 || ry > 47) continue;
            const int lr = w + ky;
            for (int kx = 0; kx < 3; ++kx) {
                const int tap = ky * 3 + kx;
                #pragma unroll
                for (int c32 = 0; c32 < 2; ++c32) {
                    bf16x8 bfr[3];
                    #pragma unroll
                    for (int nf = 0; nf < 3; ++nf) {
                        const int px = nf * 16 + col + kx + d0;
                        const int pxc = max(0, min(47, px));
                        bf16x8 tmp = *reinterpret_cast<const bf16x8*>(
                            st + (((c32 * 4 + quad) * 288) + lr * 48 + pxc) * 8);
                        bfr[nf] = (px == pxc) ? tmp : (bf16x8)(__bf16)0.f;
                    }
                    const __hip_bfloat16* wp =
                        wbase + tap * 128 + hc * 64 + c32 * 32 + quad * 8;
                    if (t != 2) {
                        #pragma unroll
                        for (int cf = 0; cf < 4; ++cf) {
                            const bf16x8 af = ldb8(wp + (size_t)(cf * 16) * 1152);
                            #pragma unroll
                            for (int nf = 0; nf < 3; ++nf)
                                acc[cf * 3 + nf] = __builtin_amdgcn_mfma_f32_16x16x32_bf16(
                                    af, bfr[nf], acc[cf * 3 + nf], 0, 0, 0);
                        }
                    } else {
                        #pragma unroll
                        for (int cf = 0; cf < 4; ++cf) {
                            const bf16x8 af = ldb8(wp + (size_t)(cf * 16) * 1152);
                            #pragma unroll
                            for (int nf = 0; nf < 3; ++nf)
                                acc[cf * 3 + nf] = __builtin_amdgcn_mfma_f32_16x16x32_bf16(
                                    bfr[nf], af, acc[cf * 3 + nf], 0, 0, 0);
                        }
                    }
                }
            }
        }
    }

    if (!wave_active) return;
    if (t == 0) {
        const float ts = tau[g];
        __hip_bfloat16* dst = qT + (size_t)ng * PP * 64;
        #pragma unroll
        for (int cf = 0; cf < 4; ++cf)
            #pragma unroll
            for (int nf = 0; nf < 3; ++nf) {
                const int pix = yy * 48 + nf * 16 + col;
                store4bf(dst + (size_t)pix * 64 + cf * 16 + quad * 4,
                         acc[cf * 3 + nf] * ts);
            }
    } else if (t == 1) {
        __hip_bfloat16* dst = kT + (size_t)ng * DD * 64;
        #pragma unroll
        for (int cf = 0; cf < 4; ++cf)
            #pragma unroll
            for (int nf = 0; nf < 3; ++nf) {
                const int x = nf * 16 + col;
                if (x < 46) {
                    const int pix = yy * 46 + x;
                    store4bf(dst + (size_t)pix * 64 + cf * 16 + quad * 4, acc[cf * 3 + nf]);
                }
            }
    } else {
        __hip_bfloat16* dst = v + (size_t)ng * 64 * DPADV;
        #pragma unroll
        for (int cf = 0; cf < 4; ++cf) {
            const int co = cf * 16 + col;
            #pragma unroll
            for (int nf = 0; nf < 3; ++nf) {
                const int x4 = nf * 16 + quad * 4;
                #pragma unroll
                for (int r = 0; r < 4; ++r) {
                    if (x4 + r < 46)
                        dst[(size_t)co * DPADV + yy * 46 + x4 + r] =
                            (__hip_bfloat16)acc[cf * 3 + nf][r];
                }
            }
        }
    }
}

// ---------------------------------------------------------------------------
// Kernel 3: MFMA flash attention, shuffle-free P^T.
// d->k slot permutation: k=quad*8+j <-> d = dbase+quad*4+j (j<4),
// dbase+16+quad*4+(j-4) (j>=4). With this map the PV B-frag is the lane's
// own exp(S) registers (no cross-lane transpose); V A-frag = two 8B loads.
// Block = 16 q-rows x 4 D-split waves; LDS merge; grid 2304 x 256.
// ---------------------------------------------------------------------------
template<bool MASKED>
__device__ __forceinline__ void attn_tile(
    const int dbase, const __hip_bfloat16* __restrict__ kbase,
    const __hip_bfloat16* __restrict__ vbase,
    const bf16x8 qf0, const bf16x8 qf1,
    float& m, float& l, f32x4* acc, const int col, const int quad)
{
    const f32x4 zero = {0.f, 0.f, 0.f, 0.f};
    int dr0 = dbase + col, dr1 = dbase + 16 + col;
    if (MASKED) { dr0 = min(dr0, DD - 1); dr1 = min(dr1, DD - 1); }
    const __hip_bfloat16* k0 = kbase + (size_t)dr0 * CGR + quad * 8;
    const __hip_bfloat16* k1 = kbase + (size_t)dr1 * CGR + quad * 8;
    f32x4 S0 = __builtin_amdgcn_mfma_f32_16x16x32_bf16(ldb8(k0), qf0, zero, 0, 0, 0);
    S0 = __builtin_amdgcn_mfma_f32_16x16x32_bf16(ldb8(k0 + 32), qf1, S0, 0, 0, 0);
    f32x4 S1 = __builtin_amdgcn_mfma_f32_16x16x32_bf16(ldb8(k1), qf0, zero, 0, 0, 0);
    S1 = __builtin_amdgcn_mfma_f32_16x16x32_bf16(ldb8(k1 + 32), qf1, S1, 0, 0, 0);

    float e[8];
    #pragma unroll
    for (int r = 0; r < 4; ++r) { e[r] = S0[r]; e[4 + r] = S1[r]; }
    if (MASKED) {
        #pragma unroll
        for (int r = 0; r < 4; ++r) {
            if (dbase + quad * 4 + r >= DD) e[r] = -1e30f;
            if (dbase + 16 + quad * 4 + r >= DD) e[4 + r] = -1e30f;
        }
    }

    float smax = fmaxf(fmaxf(fmaxf(e[0], e[1]), fmaxf(e[2], e[3])),
                       fmaxf(fmaxf(e[4], e[5]), fmaxf(e[6], e[7])));
    smax = fmaxf(smax, __shfl_xor(smax, 16, 64));
    smax = fmaxf(smax, __shfl_xor(smax, 32, 64));
    const float mnew = fmaxf(m, smax);
    const float alpha = __expf(m - mnew);
    float lsum = 0.f;
    #pragma unroll
    for (int jj = 0; jj < 8; ++jj) { e[jj] = __expf(e[jj] - mnew); lsum += e[jj]; }
    lsum += __shfl_xor(lsum, 16, 64);
    lsum += __shfl_xor(lsum, 32, 64);
    l = l * alpha + lsum;
    m = mnew;

    bf16x8 pt;
    #pragma unroll
    for (int jj = 0; jj < 8; ++jj) pt[jj] = (__bf16)e[jj];

    int da = dbase + quad * 4, db = dbase + 16 + quad * 4;
    if (MASKED) { da = min(da, DD - 4); db = min(db, DD - 4); }
    #pragma unroll
    for (int cf = 0; cf < 4; ++cf) {
        acc[cf] *= alpha;
        const __hip_bfloat16* vrow = vbase + (size_t)(cf * 16 + col) * DPADV;
        const bf16x4 va = *reinterpret_cast<const bf16x4*>(vrow + da);
        const bf16x4 vb = *reinterpret_cast<const bf16x4*>(vrow + db);
        const bf16x8 af = __builtin_shufflevector(va, vb, 0, 1, 2, 3, 4, 5, 6, 7);
        acc[cf] = __builtin_amdgcn_mfma_f32_16x16x32_bf16(af, pt, acc[cf], 0, 0, 0);
    }
}

__global__ __launch_bounds__(256) void attn_kernel(
    __hip_bfloat16* qa,                      // qT in (tau-scaled), aT out
    const __hip_bfloat16* __restrict__ kT,
    const __hip_bfloat16* __restrict__ vT)
{
    const int idx = blockIdx.x;              // 0..2303, idx&7 = group
    const int g = idx & 7;
    const int r = idx >> 3;                  // 0..287
    const int nn = (r >= 144) ? 1 : 0;
    const int qt = r - nn * 144;             // 0..143
    const int ng = g + 8 * nn;
    const int tid = threadIdx.x;
    const int w = tid >> 6, lane = tid & 63;
    const int col = lane & 15, quad = lane >> 4;
    const int qbase = qt * 16;

    __shared__ float accs[4 * 64 * 17];      // stride 17: conflict-free merge
    __shared__ float sml[4 * 32];

    __hip_bfloat16* qrow = qa + ((size_t)ng * PP + qbase + col) * CGR;
    const bf16x8 qf0 = ldb8(qrow + quad * 8);
    const bf16x8 qf1 = ldb8(qrow + 32 + quad * 8);

    const __hip_bfloat16* kbase = kT + (size_t)ng * DD * CGR;
    const __hip_bfloat16* vbase = vT + (size_t)ng * CGR * DPADV;

    f32x4 acc[4];
    #pragma unroll
    for (int cf = 0; cf < 4; ++cf) acc[cf] = (f32x4){0.f, 0.f, 0.f, 0.f};
    float m = -INFINITY, l = 0.f;

    // 67 tiles of 32 keys; waves 0-2: 17 each, wave 3: 15 + masked tail.
    const int i0 = w * 17;
    const int iend = min(i0 + 17, 66);
    for (int it = i0; it < iend; ++it)
        attn_tile<false>(it * 32, kbase, vbase, qf0, qf1, m, l, acc, col, quad);
    if (w == 3)
        attn_tile<true>(66 * 32, kbase, vbase, qf0, qf1, m, l, acc, col, quad);

    // merge the 4 D-splits through LDS
    const int wl = w * 64 + lane;
    #pragma unroll
    for (int cf = 0; cf < 4; ++cf)
        #pragma unroll
        for (int r2 = 0; r2 < 4; ++r2)
            accs[wl * 17 + cf * 4 + r2] = acc[cf][r2];
    if (lane < 16) { sml[w * 32 + lane] = m; sml[w * 32 + 16 + lane] = l; }
    __syncthreads();

    if (w != 0) return;
    const float m0 = sml[col], m1 = sml[32 + col],
                m2 = sml[64 + col], m3 = sml[96 + col];
    const float ms = fmaxf(fmaxf(m0, m1), fmaxf(m2, m3));
    const float s0 = __expf(m0 - ms), s1 = __expf(m1 - ms),
                s2 = __expf(m2 - ms), s3 = __expf(m3 - ms);
    const float L = sml[16 + col] * s0 + sml[48 + col] * s1 +
                    sml[80 + col] * s2 + sml[112 + col] * s3;
    const float inv = 1.f / L;
    #pragma unroll
    for (int cf = 0; cf < 4; ++cf) {
        f32x4 res;
        #pragma unroll
        for (int r2 = 0; r2 < 4; ++r2) {
            const int o = cf * 4 + r2;
            res[r2] = (accs[lane * 17 + o] * s0 +
                       accs[(64 + lane) * 17 + o] * s1 +
                       accs[(128 + lane) * 17 + o] * s2 +
                       accs[(192 + lane) * 17 + o] * s3) * inv;
        }
        store4bf(qrow + cf * 16 + quad * 4, res);
    }
}

// ---------------------------------------------------------------------------
// Kernel 4: fused gates via MFMA + LSTM update (unchanged). grid 768 x 256.
// ---------------------------------------------------------------------------
__global__ __launch_bounds__(256) void gates_kernel(
    const __hip_bfloat16* __restrict__ xhT, const __hip_bfloat16* __restrict__ aT,
    const float* __restrict__ c_in,
    const __hip_bfloat16* __restrict__ Wr, const __hip_bfloat16* __restrict__ Wa,
    const float* __restrict__ b_i, const float* __restrict__ b_f,
    const float* __restrict__ b_g, const float* __restrict__ b_o,
    float* __restrict__ h_out)
{
    const int b = blockIdx.x;
    const int xcd = b & 7;
    const int j = b >> 3;
    const int ng = xcd + 8 * (j / 48);
    const int yy = j % 48;
    const int n = ng >> 3, g = ng & 7;
    const int tid = threadIdx.x;
    const int w = tid >> 6, lane = tid & 63;
    const int col = lane & 15, quad = lane >> 4;

    __shared__ char smem[16 * 144 * 8 * 2];
    __hip_bfloat16* st = (__hip_bfloat16*)smem;
    float* ex = (float*)smem;

    const __hip_bfloat16* slab = xhT + (size_t)ng * PP * 128;

    #pragma unroll
    for (int it = 0; it < 9; ++it) {
        const int u = it * 256 + tid;
        const int lr = u / 768;
        const int rem = u % 768;
        const int px = rem >> 4, ck = rem & 15;
        int ry = yy - 1 + lr;
        ry = max(0, min(47, ry));
        *reinterpret_cast<bf16x8*>(st + ((ck * 144) + lr * 48 + px) * 8) =
            ldb8(slab + ((size_t)(ry * 48 + px)) * 128 + ck * 8);
    }
    __syncthreads();

    f32x4 acc[12];
    #pragma unroll
    for (int i = 0; i < 12; ++i) acc[i] = (f32x4){0.f, 0.f, 0.f, 0.f};

    const __hip_bfloat16* wbase =
        Wr + (size_t)(3 + w) * WRT + ((size_t)(g * 64) + col) * 1152;

    for (int ky = 0; ky < 3; ++ky) {
        const int ry = yy + ky - 1;
        if (ry < 0 || ry > 47) continue;
        const int lr = ky;
        for (int kx = 0; kx < 3; ++kx) {
            const int tap = ky * 3 + kx;
            #pragma unroll
            for (int c32 = 0; c32 < 4; ++c32) {
                bf16x8 bfr[3];
                #pragma unroll
                for (int nf = 0; nf < 3; ++nf) {
                    const int px = nf * 16 + col + kx - 1;
                    const int pxc = max(0, min(47, px));
                    bf16x8 tmp = *reinterpret_cast<const bf16x8*>(
                        st + (((c32 * 4 + quad) * 144) + lr * 48 + pxc) * 8);
                    bfr[nf] = (px == pxc) ? tmp : (bf16x8)(__bf16)0.f;
                }
                const __hip_bfloat16* wp = wbase + tap * 128 + c32 * 32 + quad * 8;
                #pragma unroll
                for (int cf = 0; cf < 4; ++cf) {
                    const bf16x8 af = ldb8(wp + (size_t)(cf * 16) * 1152);
                    #pragma unroll
                    for (int nf = 0; nf < 3; ++nf)
                        acc[cf * 3 + nf] = __builtin_amdgcn_mfma_f32_16x16x32_bf16(
                            af, bfr[nf], acc[cf * 3 + nf], 0, 0, 0);
                }
            }
        }
    }

    {
        const __hip_bfloat16* wa =
            Wa + (size_t)w * 32768 + ((size_t)(g * 64) + col) * 64;
        const __hip_bfloat16* ab = aT + ((size_t)ng * PP + yy * 48) * 64;
        #pragma unroll
        for (int c32 = 0; c32 < 2; ++c32) {
            bf16x8 bfr[3];
            #pragma unroll
            for (int nf = 0; nf < 3; ++nf)
                bfr[nf] = ldb8(ab + (size_t)(nf * 16 + col) * 64 + c32 * 32 + quad * 8);
            #pragma unroll
            for (int cf = 0; cf < 4; ++cf) {
                const bf16x8 af = ldb8(wa + (size_t)(cf * 16) * 64 + c32 * 32 + quad * 8);
                #pragma unroll
                for (int nf = 0; nf < 3; ++nf)
                    acc[cf * 3 + nf] = __builtin_amdgcn_mfma_f32_16x16x32_bf16(
                        af, bfr[nf], acc[cf * 3 + nf], 0, 0, 0);
            }
        }
    }

    const float* bias = (w == 0) ? b_i : (w == 1) ? b_f : (w == 2) ? b_g : b_o;
    #pragma unroll
    for (int cf = 0; cf < 4; ++cf) {
        #pragma unroll
        for (int r = 0; r < 4; ++r) {
            const float bv = bias[g * 64 + cf * 16 + quad * 4 + r];
            #pragma unroll
            for (int nf = 0; nf < 3; ++nf)
                acc[cf * 3 + nf][r] += bv;
        }
    }

    for (int hh = 0; hh < 2; ++hh) {
        __syncthreads();
        #pragma unroll
        for (int cc = 0; cc < 2; ++cc) {
            const int cf = 2 * hh + cc;
            #pragma unroll
            for (int nf = 0; nf < 3; ++nf)
                #pragma unroll
                for (int r = 0; r < 4; ++r)
                    ex[(size_t)w * 1536 + (cc * 16 + quad * 4 + r) * 48 + nf * 16 + col] =
                        acc[cf * 3 + nf][r];
        }
        __syncthreads();
        #pragma unroll
        for (int k2 = 0; k2 < 6; ++k2) {
            const int idx = k2 * 256 + tid;
            const int co32 = idx / 48, px = idx % 48;
            const float iv = ex[0 * 1536 + co32 * 48 + px];
            const float fv = ex[1 * 1536 + co32 * 48 + px];
            const float gv = ex[2 * 1536 + co32 * 48 + px];
            const float ov = ex[3 * 1536 + co32 * 48 + px];
            const int c = g * 64 + hh * 32 + co32;
            const size_t off = ((size_t)n * CC + c) * PP + yy * 48 + px;
            const float ig = 1.f / (1.f + __expf(-iv));
            const float fg = 1.f / (1.f + __expf(-fv));
            const float gg = tanhf(gv);
            const float og = 1.f / (1.f + __expf(-ov));
            const float cn = fg * c_in[off] + ig * gg;
            h_out[off] = og * tanhf(cn);
        }
    }
}

// ---------------------------------------------------------------------------
extern "C" void kernel_launch(void* const* d_in, const int* in_sizes, int n_in,
                              void* d_out, int out_size, void* d_ws, size_t ws_size,
                              hipStream_t stream)
{
    const float* x_in = (const float*)d_in[0];
    const float* h    = (const float*)d_in[1];
    const float* c    = (const float*)d_in[2];
    const float* tau  = (const float*)d_in[3];
    const float* W_x  = (const float*)d_in[4];
    const float* W_ig = (const float*)d_in[5];
    const float* W_q  = (const float*)d_in[6];
    const float* W_k  = (const float*)d_in[7];
    const float* W_v  = (const float*)d_in[8];
    const float* Wi_a = (const float*)d_in[9];
    const float* Wi_x = (const float*)d_in[10];
    const float* b_i  = (const float*)d_in[11];
    const float* Wf_a = (const float*)d_in[12];
    const float* Wf_x = (const float*)d_in[13];
    const float* b_f  = (const float*)d_in[14];
    const float* Wg_a = (const float*)d_in[15];
    const float* Wg_x = (const float*)d_in[16];
    const float* b_g  = (const float*)d_in[17];
    const float* Wo_a = (const float*)d_in[18];
    const float* Wo_x = (const float*)d_in[19];
    const float* b_o  = (const float*)d_in[20];
    float* out = (float*)d_out;

    // Workspace (bf16 elements), total 34,496,512 B (~32.9 MB)
    __hip_bfloat16* wsb = (__hip_bfloat16*)d_ws;
    __hip_bfloat16* xhT = wsb;                        // 4,718,592
    __hip_bfloat16* qa  = xhT + (size_t)4718592;      // 2,359,296
    __hip_bfloat16* kT  = qa  + (size_t)2359296;      // 2,166,784
    __hip_bfloat16* vv  = kT  + (size_t)2166784;      // 2,170,880
    __hip_bfloat16* Wr  = vv  + (size_t)2170880;      // 4,128,768
    __hip_bfloat16* Wa  = Wr  + (size_t)4128768;      //   131,072
    __hip_bfloat16* Wp  = Wa  + (size_t)131072;       //   393,216
    __hip_bfloat16* xiT = Wp  + (size_t)393216;       // 1,179,648

    dim3 blk(256);
    prep_kernel<<<dim3(18176), blk, 0, stream>>>(
        W_q, W_k, W_v, Wi_x, Wf_x, Wg_x, Wo_x, Wi_a, Wf_a, Wg_a, Wo_a,
        W_x, W_ig, Wr, Wa, Wp);
    xpose_kernel<<<dim3(144, NB), blk, 0, stream>>>(x_in, h, xiT, xhT);
    proj_mfma_kernel<<<dim3(192), blk, 0, stream>>>(xiT, Wp, xhT);
    conv_qkv_kernel<<<dim3(576), blk, 0, stream>>>(xhT, Wr, tau, qa, kT, vv);
    attn_kernel<<<dim3(2304), blk, 0, stream>>>(qa, kT, vv);
    gates_kernel<<<dim3(768), blk, 0, stream>>>(
        xhT, qa, c, Wr, Wa, b_i, b_f, b_g, b_o, out);
}

// Round 7
// 402.107 us; speedup vs baseline: 1.0291x; 1.0291x over previous
//
#include <hip/hip_runtime.h>
#include <hip/hip_bf16.h>
#include <math.h>

// Problem constants
#define NB   2
#define CIN  256
#define CC   512
#define GG   8
#define CGR  64
#define HH   48
#define WW   48
#define PP   (HH*WW)        // 2304
#define HD   46
#define WD   46
#define DD   (HD*WD)        // 2116
#define DPADV 2120          // v row stride (16B-aligned rows)
#define WRT  589824         // 512*9*128, per-tensor reordered weight stride

typedef __bf16 bf16x8 __attribute__((ext_vector_type(8)));
typedef float  f32x4  __attribute__((ext_vector_type(4)));

__device__ __forceinline__ bf16x8 ldb8(const __hip_bfloat16* p) {
    return *reinterpret_cast<const bf16x8*>(p);
}
__device__ __forceinline__ void store4bf(__hip_bfloat16* p, f32x4 v) {
    union { __hip_bfloat16 h[4]; uint2 u; } t;
    #pragma unroll
    for (int r = 0; r < 4; ++r) t.h[r] = (__hip_bfloat16)v[r];
    *reinterpret_cast<uint2*>(p) = t.u;
}

// ---------------------------------------------------------------------------
// Kernel 0: weight prep (unchanged).
// ---------------------------------------------------------------------------
__global__ __launch_bounds__(256) void prep_kernel(
    const float* __restrict__ Wq, const float* __restrict__ Wk,
    const float* __restrict__ Wv, const float* __restrict__ Wix,
    const float* __restrict__ Wfx, const float* __restrict__ Wgx,
    const float* __restrict__ Wox, const float* __restrict__ Wia,
    const float* __restrict__ Wfa, const float* __restrict__ Wga,
    const float* __restrict__ Woa, const float* __restrict__ Wx,
    const float* __restrict__ Wig,
    __hip_bfloat16* __restrict__ Wr, __hip_bfloat16* __restrict__ Wa,
    __hip_bfloat16* __restrict__ Wp)
{
    const int i = blockIdx.x * 256 + threadIdx.x;
    const int N1 = 7 * WRT;
    const int N2 = N1 + 4 * 32768;
    if (i < N1) {
        const int t = i / WRT, r = i % WRT;
        const int co = r / 1152, r2 = r % 1152;
        const int tap = r2 / 128, ci = r2 % 128;
        const float* src;
        switch (t) {
            case 0: src = Wq;  break;  case 1: src = Wk;  break;
            case 2: src = Wv;  break;  case 3: src = Wix; break;
            case 4: src = Wfx; break;  case 5: src = Wgx; break;
            default: src = Wox;
        }
        Wr[i] = (__hip_bfloat16)src[(size_t)co * 1152 + ci * 9 + tap];
    } else if (i < N2) {
        const int j = i - N1;
        const int t = j / 32768, r = j % 32768;
        const float* src = (t == 0) ? Wia : (t == 1) ? Wfa : (t == 2) ? Wga : Woa;
        Wa[j] = (__hip_bfloat16)src[r];
    } else {
        const int j = i - N2;
        const int c = j / 768, k = j % 768;
        Wp[j] = (__hip_bfloat16)((k < 256) ? Wx[(size_t)c * 256 + k]
                                           : Wig[(size_t)c * 512 + (k - 256)]);
    }
}

// ---------------------------------------------------------------------------
// Kernel 1a: transpose/convert (unchanged).
// ---------------------------------------------------------------------------
__global__ __launch_bounds__(256) void xpose_kernel(
    const float* __restrict__ x_in, const float* __restrict__ h,
    __hip_bfloat16* __restrict__ xiT, __hip_bfloat16* __restrict__ xhT)
{
    const int pt = blockIdx.x;
    const int n  = blockIdx.y;
    const int p0 = pt * 16;
    const int tid = threadIdx.x;

    __shared__ float xs[CIN * 17];
    __shared__ float hs[CC * 17];

    const float* xb = x_in + (size_t)n * CIN * PP;
    const float* hb = h + (size_t)n * CC * PP;
    #pragma unroll
    for (int k = 0; k < 16; ++k) {
        const int idx = k * 256 + tid;
        xs[(idx >> 4) * 17 + (idx & 15)] = xb[(size_t)(idx >> 4) * PP + p0 + (idx & 15)];
    }
    #pragma unroll
    for (int k = 0; k < 32; ++k) {
        const int idx = k * 256 + tid;
        hs[(idx >> 4) * 17 + (idx & 15)] = hb[(size_t)(idx >> 4) * PP + p0 + (idx & 15)];
    }
    __syncthreads();

    #pragma unroll
    for (int it = 0; it < 2; ++it) {
        const int u = it * 256 + tid;
        const int pix = u & 15, ck = u >> 4;
        union { __hip_bfloat16 h8[8]; bf16x8 v; } t;
        #pragma unroll
        for (int j = 0; j < 8; ++j)
            t.h8[j] = (__hip_bfloat16)xs[(ck * 8 + j) * 17 + pix];
        *reinterpret_cast<bf16x8*>(
            xiT + ((size_t)n * PP + p0 + pix) * 256 + ck * 8) = t.v;
    }
    #pragma unroll
    for (int it = 0; it < 4; ++it) {
        const int u = it * 256 + tid;
        const int pix = u & 15, ck = u >> 4;
        const int g = ck >> 3, c8 = (ck & 7) * 8;
        union { __hip_bfloat16 h8[8]; bf16x8 v; } t;
        #pragma unroll
        for (int j = 0; j < 8; ++j)
            t.h8[j] = (__hip_bfloat16)hs[(ck * 8 + j) * 17 + pix];
        *reinterpret_cast<bf16x8*>(
            xhT + ((size_t)(n * GG + g) * PP + p0 + pix) * 128 + 64 + c8) = t.v;
    }
}

// ---------------------------------------------------------------------------
// Kernel 1b: proj GEMM via MFMA (unchanged). grid 192 x 256.
// ---------------------------------------------------------------------------
__global__ __launch_bounds__(256) void proj_mfma_kernel(
    const __hip_bfloat16* __restrict__ xiT, const __hip_bfloat16* __restrict__ Wp,
    __hip_bfloat16* xhT)
{
    const int b = blockIdx.x;
    const int g = b & 7;
    const int j = b >> 3;
    const int n = j / 12;
    const int yt = j % 12;
    const int ng = n * GG + g;
    const int tid = threadIdx.x;
    const int w = tid >> 6, lane = tid & 63;
    const int col = lane & 15, quad = lane >> 4;
    const int y = yt * 4 + w;

    f32x4 acc[12];
    #pragma unroll
    for (int i = 0; i < 12; ++i) acc[i] = (f32x4){0.f, 0.f, 0.f, 0.f};

    const __hip_bfloat16* wbase = Wp + ((size_t)(g * 64) + col) * 768;

    for (int kk = 0; kk < 24; ++kk) {
        bf16x8 bfr[3];
        if (kk < 8) {
            const __hip_bfloat16* bp =
                xiT + ((size_t)n * PP + y * 48 + col) * 256 + kk * 32 + quad * 8;
            #pragma unroll
            for (int nf = 0; nf < 3; ++nf)
                bfr[nf] = ldb8(bp + (size_t)(nf * 16) * 256);
        } else {
            const int kh = kk - 8;
            const int gp = kh >> 1;
            const int c0 = (kh & 1) * 32;
            const __hip_bfloat16* bp =
                xhT + ((size_t)(n * GG + gp) * PP + y * 48 + col) * 128 + 64 + c0 + quad * 8;
            #pragma unroll
            for (int nf = 0; nf < 3; ++nf)
                bfr[nf] = ldb8(bp + (size_t)(nf * 16) * 128);
        }
        const __hip_bfloat16* wp = wbase + kk * 32 + quad * 8;
        #pragma unroll
        for (int cf = 0; cf < 4; ++cf) {
            const bf16x8 af = ldb8(wp + (size_t)(cf * 16) * 768);
            #pragma unroll
            for (int nf = 0; nf < 3; ++nf)
                acc[cf * 3 + nf] = __builtin_amdgcn_mfma_f32_16x16x32_bf16(
                    af, bfr[nf], acc[cf * 3 + nf], 0, 0, 0);
        }
    }

    __hip_bfloat16* dst = xhT + (size_t)ng * PP * 128;
    #pragma unroll
    for (int cf = 0; cf < 4; ++cf)
        #pragma unroll
        for (int nf = 0; nf < 3; ++nf) {
            const int pix = y * 48 + nf * 16 + col;
            store4bf(dst + (size_t)pix * 128 + cf * 16 + quad * 4, acc[cf * 3 + nf]);
        }
}

// ---------------------------------------------------------------------------
// Kernel 2: fused q/k/v grouped 3x3 conv via MFMA (q scaled by tau).
// grid 576 x 256. (unchanged)
// ---------------------------------------------------------------------------
__global__ __launch_bounds__(256) void conv_qkv_kernel(
    const __hip_bfloat16* __restrict__ xhT, const __hip_bfloat16* __restrict__ Wr,
    const float* __restrict__ tau,
    __hip_bfloat16* __restrict__ qT, __hip_bfloat16* __restrict__ kT,
    __hip_bfloat16* __restrict__ v)
{
    const int b = blockIdx.x;
    const int xcd = b & 7;
    const int j = b >> 3;
    const int s = xcd + 8 * (j / 12);
    const int yt = j % 12;
    const int t = s / 16;
    const int ng = s % 16;
    const int g = ng & 7;
    const int tid = threadIdx.x;
    const int w = tid >> 6, lane = tid & 63;
    const int col = lane & 15, quad = lane >> 4;
    const int y0 = yt * 4;
    const int yy = y0 + w;
    const int ohw = (t == 0) ? 48 : 46;
    const int d0 = (t == 0) ? -1 : 0;
    const bool wave_active = (yy < ohw);

    __shared__ __hip_bfloat16 st[8 * 288 * 8];

    const __hip_bfloat16* slab = xhT + (size_t)ng * PP * 128;
    const __hip_bfloat16* wbase =
        Wr + (size_t)t * WRT + ((size_t)(g * 64) + col) * 1152;

    f32x4 acc[12];
    #pragma unroll
    for (int i = 0; i < 12; ++i) acc[i] = (f32x4){0.f, 0.f, 0.f, 0.f};

    for (int hc = 0; hc < 2; ++hc) {
        __syncthreads();
        #pragma unroll
        for (int it = 0; it < 9; ++it) {
            const int u = it * 256 + tid;
            const int lr = u / 384;
            const int rem = u % 384;
            const int px = rem >> 3, ck = rem & 7;
            int ry = y0 + d0 + lr;
            ry = max(0, min(47, ry));
            *reinterpret_cast<bf16x8*>(st + ((ck * 288) + lr * 48 + px) * 8) =
                ldb8(slab + ((size_t)(ry * 48 + px)) * 128 + hc * 64 + ck * 8);
        }
        __syncthreads();
        if (!wave_active) continue;

        for (int ky = 0; ky < 3; ++ky) {
            const int ry = yy + ky + d0;
            if (ry < 0 || ry > 47) continue;
            const int lr = w + ky;
            for (int kx = 0; kx < 3; ++kx) {
                const int tap = ky * 3 + kx;
                #pragma unroll
                for (int c32 = 0; c32 < 2; ++c32) {
                    bf16x8 bfr[3];
                    #pragma unroll
                    for (int nf = 0; nf < 3; ++nf) {
                        const int px = nf * 16 + col + kx + d0;
                        const int pxc = max(0, min(47, px));
                        bf16x8 tmp = *reinterpret_cast<const bf16x8*>(
                            st + (((c32 * 4 + quad) * 288) + lr * 48 + pxc) * 8);
                        bfr[nf] = (px == pxc) ? tmp : (bf16x8)(__bf16)0.f;
                    }
                    const __hip_bfloat16* wp =
                        wbase + tap * 128 + hc * 64 + c32 * 32 + quad * 8;
                    if (t != 2) {
                        #pragma unroll
                        for (int cf = 0; cf < 4; ++cf) {
                            const bf16x8 af = ldb8(wp + (size_t)(cf * 16) * 1152);
                            #pragma unroll
                            for (int nf = 0; nf < 3; ++nf)
                                acc[cf * 3 + nf] = __builtin_amdgcn_mfma_f32_16x16x32_bf16(
                                    af, bfr[nf], acc[cf * 3 + nf], 0, 0, 0);
                        }
                    } else {
                        #pragma unroll
                        for (int cf = 0; cf < 4; ++cf) {
                            const bf16x8 af = ldb8(wp + (size_t)(cf * 16) * 1152);
                            #pragma unroll
                            for (int nf = 0; nf < 3; ++nf)
                                acc[cf * 3 + nf] = __builtin_amdgcn_mfma_f32_16x16x32_bf16(
                                    bfr[nf], af, acc[cf * 3 + nf], 0, 0, 0);
                        }
                    }
                }
            }
        }
    }

    if (!wave_active) return;
    if (t == 0) {
        const float ts = tau[g];
        __hip_bfloat16* dst = qT + (size_t)ng * PP * 64;
        #pragma unroll
        for (int cf = 0; cf < 4; ++cf)
            #pragma unroll
            for (int nf = 0; nf < 3; ++nf) {
                const int pix = yy * 48 + nf * 16 + col;
                store4bf(dst + (size_t)pix * 64 + cf * 16 + quad * 4,
                         acc[cf * 3 + nf] * ts);
            }
    } else if (t == 1) {
        __hip_bfloat16* dst = kT + (size_t)ng * DD * 64;
        #pragma unroll
        for (int cf = 0; cf < 4; ++cf)
            #pragma unroll
            for (int nf = 0; nf < 3; ++nf) {
                const int x = nf * 16 + col;
                if (x < 46) {
                    const int pix = yy * 46 + x;
                    store4bf(dst + (size_t)pix * 64 + cf * 16 + quad * 4, acc[cf * 3 + nf]);
                }
            }
    } else {
        __hip_bfloat16* dst = v + (size_t)ng * 64 * DPADV;
        #pragma unroll
        for (int cf = 0; cf < 4; ++cf) {
            const int co = cf * 16 + col;
            #pragma unroll
            for (int nf = 0; nf < 3; ++nf) {
                const int x4 = nf * 16 + quad * 4;
                #pragma unroll
                for (int r = 0; r < 4; ++r) {
                    if (x4 + r < 46)
                        dst[(size_t)co * DPADV + yy * 46 + x4 + r] =
                            (__hip_bfloat16)acc[cf * 3 + nf][r];
                }
            }
        }
    }
}

// ---------------------------------------------------------------------------
// Kernel 3: MFMA flash attention. Wave = 16 q over FULL D sweep (no split,
// no LDS, no merge). Shuffle-free P^T via key->A-row permutation
// key = (m>>2)*8 + (m&3) (+4 for 2nd MFMA): lane(quad) then owns keys
// dbase+quad*8+{0..7} == the PV B-frag slots, and the V A-frag is ONE 16B
// load at vrow + dbase + quad*8. K-frags register-double-buffered.
// grid 576 x 256.
// ---------------------------------------------------------------------------
__global__ __launch_bounds__(256) void attn_kernel(
    __hip_bfloat16* qa,                      // qT in (tau-scaled), aT out
    const __hip_bfloat16* __restrict__ kT,
    const __hip_bfloat16* __restrict__ vT)
{
    const int idx = blockIdx.x;              // 0..575, idx&7 = group
    const int j3  = idx >> 3;                // 0..71
    const int ng  = (idx & 7) + ((j3 >= 36) ? 8 : 0);
    const int qt  = j3 - ((j3 >= 36) ? 36 : 0);
    const int tid = threadIdx.x;
    const int w = tid >> 6, lane = tid & 63;
    const int col = lane & 15, quad = lane >> 4;
    const int qbase = qt * 64 + w * 16;

    __hip_bfloat16* qrow = qa + ((size_t)ng * PP + qbase + col) * CGR;
    const bf16x8 qf0 = ldb8(qrow + quad * 8);
    const bf16x8 qf1 = ldb8(qrow + 32 + quad * 8);

    const __hip_bfloat16* kbase = kT + (size_t)ng * DD * CGR;
    const __hip_bfloat16* vbase = vT + (size_t)ng * CGR * DPADV;
    const __hip_bfloat16* vrow[4];
    #pragma unroll
    for (int cf = 0; cf < 4; ++cf)
        vrow[cf] = vbase + (size_t)(cf * 16 + col) * DPADV;

    // permuted tile-local key for this lane's A-rows
    const int key0 = ((col >> 2) << 3) + (col & 3);
    const __hip_bfloat16* p0 = kbase + (size_t)key0 * CGR + quad * 8;
    const __hip_bfloat16* p1 = p0 + 4 * CGR;

    f32x4 acc[4];
    #pragma unroll
    for (int cf = 0; cf < 4; ++cf) acc[cf] = (f32x4){0.f, 0.f, 0.f, 0.f};
    float m = -INFINITY, l = 0.f;
    const f32x4 zero = {0.f, 0.f, 0.f, 0.f};

    bf16x8 A0 = ldb8(p0), A1 = ldb8(p0 + 32);
    bf16x8 B0 = ldb8(p1), B1 = ldb8(p1 + 32);

    for (int it = 0; it < 66; ++it) {
        const int dbase = it * 32;
        p0 += 32 * CGR; p1 += 32 * CGR;
        bf16x8 nA0, nA1, nB0, nB1;
        if (it < 65) {                       // uniform branch: prefetch next
            nA0 = ldb8(p0); nA1 = ldb8(p0 + 32);
            nB0 = ldb8(p1); nB1 = ldb8(p1 + 32);
        }

        f32x4 S0 = __builtin_amdgcn_mfma_f32_16x16x32_bf16(A0, qf0, zero, 0, 0, 0);
        S0 = __builtin_amdgcn_mfma_f32_16x16x32_bf16(A1, qf1, S0, 0, 0, 0);
        f32x4 S1 = __builtin_amdgcn_mfma_f32_16x16x32_bf16(B0, qf0, zero, 0, 0, 0);
        S1 = __builtin_amdgcn_mfma_f32_16x16x32_bf16(B1, qf1, S1, 0, 0, 0);

        float smax = fmaxf(fmaxf(fmaxf(S0[0], S0[1]), fmaxf(S0[2], S0[3])),
                           fmaxf(fmaxf(S1[0], S1[1]), fmaxf(S1[2], S1[3])));
        smax = fmaxf(smax, __shfl_xor(smax, 16, 64));
        smax = fmaxf(smax, __shfl_xor(smax, 32, 64));
        const float mnew = fmaxf(m, smax);
        const float alpha = __expf(m - mnew);
        float e[8];
        float lsum = 0.f;
        #pragma unroll
        for (int r = 0; r < 4; ++r) {
            e[r]     = __expf(S0[r] - mnew);
            e[4 + r] = __expf(S1[r] - mnew);
            lsum += e[r] + e[4 + r];
        }
        lsum += __shfl_xor(lsum, 16, 64);
        lsum += __shfl_xor(lsum, 32, 64);
        l = l * alpha + lsum;
        m = mnew;

        bf16x8 pt;
        #pragma unroll
        for (int jj = 0; jj < 8; ++jj) pt[jj] = (__bf16)e[jj];

        const int da = dbase + quad * 8;
        #pragma unroll
        for (int cf = 0; cf < 4; ++cf) {
            acc[cf] *= alpha;
            acc[cf] = __builtin_amdgcn_mfma_f32_16x16x32_bf16(
                ldb8(vrow[cf] + da), pt, acc[cf], 0, 0, 0);
        }
        A0 = nA0; A1 = nA1; B0 = nB0; B1 = nB1;
    }

    // ---- masked tail tile: keys 2112..2143, valid < 2116 ----
    {
        const int dbase = 66 * 32;
        const int kk0 = min(dbase + key0, DD - 1);
        const int kk1 = min(dbase + key0 + 4, DD - 1);
        const __hip_bfloat16* t0 = kbase + (size_t)kk0 * CGR + quad * 8;
        const __hip_bfloat16* t1 = kbase + (size_t)kk1 * CGR + quad * 8;
        f32x4 S0 = __builtin_amdgcn_mfma_f32_16x16x32_bf16(ldb8(t0), qf0, zero, 0, 0, 0);
        S0 = __builtin_amdgcn_mfma_f32_16x16x32_bf16(ldb8(t0 + 32), qf1, S0, 0, 0, 0);
        f32x4 S1 = __builtin_amdgcn_mfma_f32_16x16x32_bf16(ldb8(t1), qf0, zero, 0, 0, 0);
        S1 = __builtin_amdgcn_mfma_f32_16x16x32_bf16(ldb8(t1 + 32), qf1, S1, 0, 0, 0);

        float e[8];
        #pragma unroll
        for (int r = 0; r < 4; ++r) {
            e[r]     = (dbase + quad * 8 + r     < DD) ? S0[r] : -1e30f;
            e[4 + r] = (dbase + quad * 8 + 4 + r < DD) ? S1[r] : -1e30f;
        }
        float smax = fmaxf(fmaxf(fmaxf(e[0], e[1]), fmaxf(e[2], e[3])),
                           fmaxf(fmaxf(e[4], e[5]), fmaxf(e[6], e[7])));
        smax = fmaxf(smax, __shfl_xor(smax, 16, 64));
        smax = fmaxf(smax, __shfl_xor(smax, 32, 64));
        const float mnew = fmaxf(m, smax);
        const float alpha = __expf(m - mnew);
        float lsum = 0.f;
        #pragma unroll
        for (int jj = 0; jj < 8; ++jj) { e[jj] = __expf(e[jj] - mnew); lsum += e[jj]; }
        lsum += __shfl_xor(lsum, 16, 64);
        lsum += __shfl_xor(lsum, 32, 64);
        l = l * alpha + lsum;
        m = mnew;

        bf16x8 pt;
        #pragma unroll
        for (int jj = 0; jj < 8; ++jj) pt[jj] = (__bf16)e[jj];

        int da = dbase + quad * 8;
        if (da >= DD) da = 0;                // fully-masked quads: P==0
        #pragma unroll
        for (int cf = 0; cf < 4; ++cf) {
            acc[cf] *= alpha;
            acc[cf] = __builtin_amdgcn_mfma_f32_16x16x32_bf16(
                ldb8(vrow[cf] + da), pt, acc[cf], 0, 0, 0);
        }
    }

    const float inv = 1.f / l;
    #pragma unroll
    for (int cf = 0; cf < 4; ++cf)
        store4bf(qrow + cf * 16 + quad * 4, acc[cf] * inv);
}

// ---------------------------------------------------------------------------
// Kernel 4: fused gates via MFMA + LSTM update (unchanged). grid 768 x 256.
// ---------------------------------------------------------------------------
__global__ __launch_bounds__(256) void gates_kernel(
    const __hip_bfloat16* __restrict__ xhT, const __hip_bfloat16* __restrict__ aT,
    const float* __restrict__ c_in,
    const __hip_bfloat16* __restrict__ Wr, const __hip_bfloat16* __restrict__ Wa,
    const float* __restrict__ b_i, const float* __restrict__ b_f,
    const float* __restrict__ b_g, const float* __restrict__ b_o,
    float* __restrict__ h_out)
{
    const int b = blockIdx.x;
    const int xcd = b & 7;
    const int j = b >> 3;
    const int ng = xcd + 8 * (j / 48);
    const int yy = j % 48;
    const int n = ng >> 3, g = ng & 7;
    const int tid = threadIdx.x;
    const int w = tid >> 6, lane = tid & 63;
    const int col = lane & 15, quad = lane >> 4;

    __shared__ char smem[16 * 144 * 8 * 2];
    __hip_bfloat16* st = (__hip_bfloat16*)smem;
    float* ex = (float*)smem;

    const __hip_bfloat16* slab = xhT + (size_t)ng * PP * 128;

    #pragma unroll
    for (int it = 0; it < 9; ++it) {
        const int u = it * 256 + tid;
        const int lr = u / 768;
        const int rem = u % 768;
        const int px = rem >> 4, ck = rem & 15;
        int ry = yy - 1 + lr;
        ry = max(0, min(47, ry));
        *reinterpret_cast<bf16x8*>(st + ((ck * 144) + lr * 48 + px) * 8) =
            ldb8(slab + ((size_t)(ry * 48 + px)) * 128 + ck * 8);
    }
    __syncthreads();

    f32x4 acc[12];
    #pragma unroll
    for (int i = 0; i < 12; ++i) acc[i] = (f32x4){0.f, 0.f, 0.f, 0.f};

    const __hip_bfloat16* wbase =
        Wr + (size_t)(3 + w) * WRT + ((size_t)(g * 64) + col) * 1152;

    for (int ky = 0; ky < 3; ++ky) {
        const int ry = yy + ky - 1;
        if (ry < 0 || ry > 47) continue;
        const int lr = ky;
        for (int kx = 0; kx < 3; ++kx) {
            const int tap = ky * 3 + kx;
            #pragma unroll
            for (int c32 = 0; c32 < 4; ++c32) {
                bf16x8 bfr[3];
                #pragma unroll
                for (int nf = 0; nf < 3; ++nf) {
                    const int px = nf * 16 + col + kx - 1;
                    const int pxc = max(0, min(47, px));
                    bf16x8 tmp = *reinterpret_cast<const bf16x8*>(
                        st + (((c32 * 4 + quad) * 144) + lr * 48 + pxc) * 8);
                    bfr[nf] = (px == pxc) ? tmp : (bf16x8)(__bf16)0.f;
                }
                const __hip_bfloat16* wp = wbase + tap * 128 + c32 * 32 + quad * 8;
                #pragma unroll
                for (int cf = 0; cf < 4; ++cf) {
                    const bf16x8 af = ldb8(wp + (size_t)(cf * 16) * 1152);
                    #pragma unroll
                    for (int nf = 0; nf < 3; ++nf)
                        acc[cf * 3 + nf] = __builtin_amdgcn_mfma_f32_16x16x32_bf16(
                            af, bfr[nf], acc[cf * 3 + nf], 0, 0, 0);
                }
            }
        }
    }

    {
        const __hip_bfloat16* wa =
            Wa + (size_t)w * 32768 + ((size_t)(g * 64) + col) * 64;
        const __hip_bfloat16* ab = aT + ((size_t)ng * PP + yy * 48) * 64;
        #pragma unroll
        for (int c32 = 0; c32 < 2; ++c32) {
            bf16x8 bfr[3];
            #pragma unroll
            for (int nf = 0; nf < 3; ++nf)
                bfr[nf] = ldb8(ab + (size_t)(nf * 16 + col) * 64 + c32 * 32 + quad * 8);
            #pragma unroll
            for (int cf = 0; cf < 4; ++cf) {
                const bf16x8 af = ldb8(wa + (size_t)(cf * 16) * 64 + c32 * 32 + quad * 8);
                #pragma unroll
                for (int nf = 0; nf < 3; ++nf)
                    acc[cf * 3 + nf] = __builtin_amdgcn_mfma_f32_16x16x32_bf16(
                        af, bfr[nf], acc[cf * 3 + nf], 0, 0, 0);
            }
        }
    }

    const float* bias = (w == 0) ? b_i : (w == 1) ? b_f : (w == 2) ? b_g : b_o;
    #pragma unroll
    for (int cf = 0; cf < 4; ++cf) {
        #pragma unroll
        for (int r = 0; r < 4; ++r) {
            const float bv = bias[g * 64 + cf * 16 + quad * 4 + r];
            #pragma unroll
            for (int nf = 0; nf < 3; ++nf)
                acc[cf * 3 + nf][r] += bv;
        }
    }

    for (int hh = 0; hh < 2; ++hh) {
        __syncthreads();
        #pragma unroll
        for (int cc = 0; cc < 2; ++cc) {
            const int cf = 2 * hh + cc;
            #pragma unroll
            for (int nf = 0; nf < 3; ++nf)
                #pragma unroll
                for (int r = 0; r < 4; ++r)
                    ex[(size_t)w * 1536 + (cc * 16 + quad * 4 + r) * 48 + nf * 16 + col] =
                        acc[cf * 3 + nf][r];
        }
        __syncthreads();
        #pragma unroll
        for (int k2 = 0; k2 < 6; ++k2) {
            const int idx = k2 * 256 + tid;
            const int co32 = idx / 48, px = idx % 48;
            const float iv = ex[0 * 1536 + co32 * 48 + px];
            const float fv = ex[1 * 1536 + co32 * 48 + px];
            const float gv = ex[2 * 1536 + co32 * 48 + px];
            const float ov = ex[3 * 1536 + co32 * 48 + px];
            const int c = g * 64 + hh * 32 + co32;
            const size_t off = ((size_t)n * CC + c) * PP + yy * 48 + px;
            const float ig = 1.f / (1.f + __expf(-iv));
            const float fg = 1.f / (1.f + __expf(-fv));
            const float gg = tanhf(gv);
            const float og = 1.f / (1.f + __expf(-ov));
            const float cn = fg * c_in[off] + ig * gg;
            h_out[off] = og * tanhf(cn);
        }
    }
}

// ---------------------------------------------------------------------------
extern "C" void kernel_launch(void* const* d_in, const int* in_sizes, int n_in,
                              void* d_out, int out_size, void* d_ws, size_t ws_size,
                              hipStream_t stream)
{
    const float* x_in = (const float*)d_in[0];
    const float* h    = (const float*)d_in[1];
    const float* c    = (const float*)d_in[2];
    const float* tau  = (const float*)d_in[3];
    const float* W_x  = (const float*)d_in[4];
    const float* W_ig = (const float*)d_in[5];
    const float* W_q  = (const float*)d_in[6];
    const float* W_k  = (const float*)d_in[7];
    const float* W_v  = (const float*)d_in[8];
    const float* Wi_a = (const float*)d_in[9];
    const float* Wi_x = (const float*)d_in[10];
    const float* b_i  = (const float*)d_in[11];
    const float* Wf_a = (const float*)d_in[12];
    const float* Wf_x = (const float*)d_in[13];
    const float* b_f  = (const float*)d_in[14];
    const float* Wg_a = (const float*)d_in[15];
    const float* Wg_x = (const float*)d_in[16];
    const float* b_g  = (const float*)d_in[17];
    const float* Wo_a = (const float*)d_in[18];
    const float* Wo_x = (const float*)d_in[19];
    const float* b_o  = (const float*)d_in[20];
    float* out = (float*)d_out;

    // Workspace (bf16 elements), total 34,496,512 B (~32.9 MB)
    __hip_bfloat16* wsb = (__hip_bfloat16*)d_ws;
    __hip_bfloat16* xhT = wsb;                        // 4,718,592
    __hip_bfloat16* qa  = xhT + (size_t)4718592;      // 2,359,296
    __hip_bfloat16* kT  = qa  + (size_t)2359296;      // 2,166,784
    __hip_bfloat16* vv  = kT  + (size_t)2166784;      // 2,170,880
    __hip_bfloat16* Wr  = vv  + (size_t)2170880;      // 4,128,768
    __hip_bfloat16* Wa  = Wr  + (size_t)4128768;      //   131,072
    __hip_bfloat16* Wp  = Wa  + (size_t)131072;       //   393,216
    __hip_bfloat16* xiT = Wp  + (size_t)393216;       // 1,179,648

    dim3 blk(256);
    prep_kernel<<<dim3(18176), blk, 0, stream>>>(
        W_q, W_k, W_v, Wi_x, Wf_x, Wg_x, Wo_x, Wi_a, Wf_a, Wg_a, Wo_a,
        W_x, W_ig, Wr, Wa, Wp);
    xpose_kernel<<<dim3(144, NB), blk, 0, stream>>>(x_in, h, xiT, xhT);
    proj_mfma_kernel<<<dim3(192), blk, 0, stream>>>(xiT, Wp, xhT);
    conv_qkv_kernel<<<dim3(576), blk, 0, stream>>>(xhT, Wr, tau, qa, kT, vv);
    attn_kernel<<<dim3(576), blk, 0, stream>>>(qa, kT, vv);
    gates_kernel<<<dim3(768), blk, 0, stream>>>(
        xhT, qa, c, Wr, Wa, b_i, b_f, b_g, b_o, out);
}